// Round 1
// baseline (1007.918 us; speedup 1.0000x reference)
//
#include <hip/hip_runtime.h>
#include <math.h>

#define NLALPHA 0.2f

static __device__ __forceinline__ float sigmoidf_(float x) { return 1.f / (1.f + expf(-x)); }

// ---------------- C = A[n,128] @ W^T[128,128] + bias, optional accumulate ----------------
template<bool ACCUM>
__global__ __launch_bounds__(256) void k_gemm128(const float* __restrict__ A,
    const float* __restrict__ W, const float* __restrict__ bias,
    float* __restrict__ C, int n)
{
    // Ws: row j, float4-col c stored at [j*32 + (c ^ (j&7))]  -> bank-balanced column reads
    __shared__ float4 Ws[128 * 32];
    __shared__ float4 As[32 * 32];
    const int t = threadIdx.x;
    const int row0 = blockIdx.x * 32;

    for (int i = t; i < 128 * 32; i += 256) {
        int jj = i >> 5, c = i & 31;
        Ws[jj * 32 + (c ^ (jj & 7))] = ((const float4*)W)[i];
    }
    for (int i = t; i < 32 * 32; i += 256) {
        int r = i >> 5, c = i & 31;
        int row = row0 + r;
        As[i] = (row < n) ? ((const float4*)A)[(size_t)row * 32 + c] : make_float4(0.f, 0.f, 0.f, 0.f);
    }
    __syncthreads();

    const int j = t & 127;
    const int rh = t >> 7;   // 0/1, wave-uniform
    float acc[16];
#pragma unroll
    for (int i = 0; i < 16; ++i) acc[i] = 0.f;

    for (int c = 0; c < 32; ++c) {
        float4 w = Ws[j * 32 + (c ^ (j & 7))];
#pragma unroll
        for (int i = 0; i < 16; ++i) {
            float4 a = As[(2 * i + rh) * 32 + c];   // uniform -> LDS broadcast
            acc[i] = fmaf(a.x, w.x, fmaf(a.y, w.y, fmaf(a.z, w.z, fmaf(a.w, w.w, acc[i]))));
        }
    }
    const float bj = bias[j];
#pragma unroll
    for (int i = 0; i < 16; ++i) {
        int row = row0 + 2 * i + rh;
        if (row < n) {
            float v = acc[i] + bj;
            if (ACCUM) C[(size_t)row * 128 + j] += v;
            else       C[(size_t)row * 128 + j] = v;
        }
    }
}

// ---------------- per-row s_s = Wh.a_src, s_d = Wh.a_dst (1 wave / row) ----------------
__global__ __launch_bounds__(256) void k_ssd(const float* __restrict__ Wh,
    const float* __restrict__ a_src, const float* __restrict__ a_dst,
    float* __restrict__ s_s, float* __restrict__ s_d, int n)
{
    int wave = (int)((blockIdx.x * 256u + threadIdx.x) >> 6);
    int lane = threadIdx.x & 63;
    if (wave >= n) return;
    float2 v  = ((const float2*)Wh)[(size_t)wave * 64 + lane];
    float2 as = ((const float2*)a_src)[lane];
    float2 ad = ((const float2*)a_dst)[lane];
    float ps = v.x * as.x + v.y * as.y;
    float pd = v.x * ad.x + v.y * ad.y;
#pragma unroll
    for (int o = 32; o; o >>= 1) {
        ps += __shfl_down(ps, o);
        pd += __shfl_down(pd, o);
    }
    if (lane == 0) { s_s[wave] = ps; s_d[wave] = pd; }
}

// ---------------- CSR build: zero, hist, scan, place ----------------
__global__ void k_zero_i32(int* p, int n) {
    int i = blockIdx.x * 256 + threadIdx.x;
    if (i < n) p[i] = 0;
}
__global__ void k_hist(const int* __restrict__ dstv, int* hist, int e) {
    int i = blockIdx.x * 256 + threadIdx.x;
    if (i < e) atomicAdd(&hist[dstv[i]], 1);
}
__global__ __launch_bounds__(1024) void k_scan(const int* __restrict__ hist,
    int* __restrict__ row_start, int* __restrict__ cursor, int n)
{
    __shared__ int sums[1024];
    const int t = threadIdx.x;
    const int per = (n + 1023) >> 10;
    const int lo = t * per;
    const int hi = min(lo + per, n);
    int s = 0;
    for (int i = lo; i < hi; ++i) s += hist[i];
    sums[t] = s;
    __syncthreads();
    for (int o = 1; o < 1024; o <<= 1) {
        int add = (t >= o) ? sums[t - o] : 0;
        __syncthreads();
        sums[t] += add;
        __syncthreads();
    }
    int run = sums[t] - s;   // exclusive base
    for (int i = lo; i < hi; ++i) {
        row_start[i] = run;
        cursor[i] = run;
        run += hist[i];
    }
    if (hi == n && lo <= n) row_start[n] = run;
}
__global__ void k_place(const int* __restrict__ dstv, int* cursor, int* eidx, int e) {
    int i = blockIdx.x * 256 + threadIdx.x;
    if (i < e) {
        int p = atomicAdd(&cursor[dstv[i]], 1);
        eidx[p] = i;
    }
}

// ---------------- fused segment softmax + weighted aggregation (1 wave / node) ----------------
__global__ __launch_bounds__(256) void k_attn(const int* __restrict__ row_start,
    const int* __restrict__ eidx, const int* __restrict__ srcv,
    const float* __restrict__ s_s, const float* __restrict__ s_d,
    const float* __restrict__ a_b, const float* __restrict__ Wh,
    float* __restrict__ hp, int n)
{
    const int node = (int)((blockIdx.x * 256u + threadIdx.x) >> 6);
    const int lane = threadIdx.x & 63;
    if (node >= n) return;
    const int lo = row_start[node], hi = row_start[node + 1];
    const float sdn = s_d[node];
    const float ab = a_b[0];

    // pass 1: segment max (lane-strided)
    float m = -INFINITY;
    for (int p = lo + lane; p < hi; p += 64) {
        float ev = s_s[srcv[eidx[p]]] + sdn + ab;
        ev = ev > 0.f ? ev : NLALPHA * ev;
        m = fmaxf(m, ev);
    }
#pragma unroll
    for (int o = 32; o; o >>= 1) m = fmaxf(m, __shfl_xor(m, o));
    if (!isfinite(m)) m = 0.f;   // empty segment -> 0 per reference

    // pass 2: denom
    float den = 0.f;
    for (int p = lo + lane; p < hi; p += 64) {
        float ev = s_s[srcv[eidx[p]]] + sdn + ab;
        ev = ev > 0.f ? ev : NLALPHA * ev;
        den += expf(ev - m);
    }
#pragma unroll
    for (int o = 32; o; o >>= 1) den += __shfl_xor(den, o);
    const float dinv = 1.f / (den > 0.f ? den : 1.f);

    // pass 3: aggregate; lane owns cols 2*lane, 2*lane+1
    float2 acc = make_float2(0.f, 0.f);
    for (int p = lo; p < hi; ++p) {
        int s = srcv[eidx[p]];
        float ev = s_s[s] + sdn + ab;            // uniform across lanes
        ev = ev > 0.f ? ev : NLALPHA * ev;
        float wgt = expf(ev - m) * dinv;
        float2 v = ((const float2*)Wh)[(size_t)s * 64 + lane];
        acc.x = fmaf(wgt, v.x, acc.x);
        acc.y = fmaf(wgt, v.y, acc.y);
    }
    ((float2*)hp)[(size_t)node * 64 + lane] = acc;
}

// ---------------- fused GRU: gates computed chunk-by-chunk with LDS-staged weights ----------------
__global__ __launch_bounds__(256) void k_gru(const float* __restrict__ hp,
    const float* __restrict__ h, const float* __restrict__ Wi,
    const float* __restrict__ Whg, const float* __restrict__ bi,
    const float* __restrict__ bh, float* __restrict__ out, int n)
{
    __shared__ float4 Ws[128 * 32];
    const int t = threadIdx.x;
    const int row0 = blockIdx.x * 32;
    const int j = t & 127, rh = t >> 7;
    float rg[16], zg[16];
    float accI[16], accH[16];

    for (int c3 = 0; c3 < 3; ++c3) {
        // ---- gi chunk: stage Wi rows, dot against h_prime ----
        for (int i = t; i < 128 * 32; i += 256) {
            int jj = i >> 5, c = i & 31;
            Ws[jj * 32 + (c ^ (jj & 7))] = ((const float4*)(Wi + (size_t)c3 * 128 * 128))[i];
        }
        __syncthreads();
#pragma unroll
        for (int i = 0; i < 16; ++i) accI[i] = 0.f;
        for (int c = 0; c < 32; ++c) {
            float4 w = Ws[j * 32 + (c ^ (j & 7))];
#pragma unroll
            for (int i = 0; i < 16; ++i) {
                int row = min(row0 + 2 * i + rh, n - 1);
                float4 a = ((const float4*)hp)[(size_t)row * 32 + c];
                accI[i] = fmaf(a.x, w.x, fmaf(a.y, w.y, fmaf(a.z, w.z, fmaf(a.w, w.w, accI[i]))));
            }
        }
        __syncthreads();
        // ---- gh chunk: stage Wh_g rows, dot against h ----
        for (int i = t; i < 128 * 32; i += 256) {
            int jj = i >> 5, c = i & 31;
            Ws[jj * 32 + (c ^ (jj & 7))] = ((const float4*)(Whg + (size_t)c3 * 128 * 128))[i];
        }
        __syncthreads();
#pragma unroll
        for (int i = 0; i < 16; ++i) accH[i] = 0.f;
        for (int c = 0; c < 32; ++c) {
            float4 w = Ws[j * 32 + (c ^ (j & 7))];
#pragma unroll
            for (int i = 0; i < 16; ++i) {
                int row = min(row0 + 2 * i + rh, n - 1);
                float4 a = ((const float4*)h)[(size_t)row * 32 + c];
                accH[i] = fmaf(a.x, w.x, fmaf(a.y, w.y, fmaf(a.z, w.z, fmaf(a.w, w.w, accH[i]))));
            }
        }
        __syncthreads();

        const float bij = bi[c3 * 128 + j];
        const float bhj = bh[c3 * 128 + j];
        if (c3 == 0) {
#pragma unroll
            for (int i = 0; i < 16; ++i) rg[i] = sigmoidf_(accI[i] + bij + accH[i] + bhj);
        } else if (c3 == 1) {
#pragma unroll
            for (int i = 0; i < 16; ++i) zg[i] = sigmoidf_(accI[i] + bij + accH[i] + bhj);
        } else {
#pragma unroll
            for (int i = 0; i < 16; ++i) {
                float nv = tanhf(accI[i] + bij + rg[i] * (accH[i] + bhj));
                int row = row0 + 2 * i + rh;
                if (row < n) {
                    float hv = h[(size_t)row * 128 + j];
                    out[(size_t)row * 128 + j] = (1.f - zg[i]) * nv + zg[i] * hv;
                }
            }
        }
    }
}

extern "C" void kernel_launch(void* const* d_in, const int* in_sizes, int n_in,
                              void* d_out, int out_size, void* d_ws, size_t ws_size,
                              hipStream_t stream)
{
    const float* h     = (const float*)d_in[0];
    const int*   srcv  = (const int*)d_in[1];
    const int*   dstv  = (const int*)d_in[2];
    const float* W     = (const float*)d_in[3];
    const float* b_W   = (const float*)d_in[4];
    const float* a_src = (const float*)d_in[5];
    const float* a_dst = (const float*)d_in[6];
    const float* a_b   = (const float*)d_in[7];
    const float* res_W = (const float*)d_in[8];
    const float* res_b = (const float*)d_in[9];
    const float* Wi    = (const float*)d_in[10];
    const float* Whg   = (const float*)d_in[11];
    const float* bi    = (const float*)d_in[12];
    const float* bh    = (const float*)d_in[13];
    float* out = (float*)d_out;
    const int n = in_sizes[0] / 128;
    const int e = in_sizes[1];

    char* p = (char*)d_ws;
    auto carve = [&](size_t bytes) -> char* {
        char* r = p;
        p += (bytes + 255) & ~(size_t)255;
        return r;
    };
    float* Wh        = (float*)carve((size_t)n * 128 * 4);
    float* hp        = (float*)carve((size_t)n * 128 * 4);
    float* s_s       = (float*)carve((size_t)n * 4);
    float* s_d       = (float*)carve((size_t)n * 4);
    int*   hist      = (int*)carve((size_t)n * 4);
    int*   row_start = (int*)carve((size_t)(n + 1) * 4);
    int*   cursor    = (int*)carve((size_t)n * 4);
    int*   eidx      = (int*)carve((size_t)e * 4);

    k_zero_i32<<<(n + 255) / 256, 256, 0, stream>>>(hist, n);
    k_gemm128<false><<<(n + 31) / 32, 256, 0, stream>>>(h, W, b_W, Wh, n);
    k_ssd<<<(n + 3) / 4, 256, 0, stream>>>(Wh, a_src, a_dst, s_s, s_d, n);
    k_hist<<<(e + 255) / 256, 256, 0, stream>>>(dstv, hist, e);
    k_scan<<<1, 1024, 0, stream>>>(hist, row_start, cursor, n);
    k_place<<<(e + 255) / 256, 256, 0, stream>>>(dstv, cursor, eidx, e);
    k_attn<<<((size_t)n * 64 + 255) / 256, 256, 0, stream>>>(row_start, eidx, srcv, s_s, s_d, a_b, Wh, hp, n);
    k_gemm128<true><<<(n + 31) / 32, 256, 0, stream>>>(h, res_W, res_b, hp, n);
    k_gru<<<(n + 31) / 32, 256, 0, stream>>>(hp, h, Wi, Whg, bi, bh, out, n);
}

// Round 2
// 326.563 us; speedup vs baseline: 3.0864x; 3.0864x over previous
//
#include <hip/hip_runtime.h>
#include <math.h>

#define NLALPHA 0.2f

typedef __attribute__((ext_vector_type(8))) short bf16x8;
typedef __attribute__((ext_vector_type(4))) float f32x4;

static __device__ __forceinline__ float sigmoidf_(float x) { return 1.f / (1.f + expf(-x)); }
static __device__ __forceinline__ unsigned short f2bf(float f) {
    unsigned int u = __float_as_uint(f);
    return (unsigned short)((u + 0x7fffu + ((u >> 16) & 1u)) >> 16);
}
static __device__ __forceinline__ float bf2f(unsigned short b) {
    return __uint_as_float(((unsigned int)b) << 16);
}

// ---- prep: convert weights to bf16, concat [W;res_W] and biases, zero hist ----
__global__ __launch_bounds__(256) void k_prep(const float* __restrict__ W,
    const float* __restrict__ res_W, const float* __restrict__ b_W,
    const float* __restrict__ res_b, const float* __restrict__ Wi,
    const float* __restrict__ Whg, unsigned short* __restrict__ Wcat,
    unsigned short* __restrict__ Wi_bf, unsigned short* __restrict__ Whg_bf,
    float* __restrict__ bias_cat, int* __restrict__ hist, int n)
{
    int i = blockIdx.x * 256 + threadIdx.x;
    if (i < 32768) Wcat[i] = f2bf(i < 16384 ? W[i] : res_W[i - 16384]);
    if (i < 49152) { Wi_bf[i] = f2bf(Wi[i]); Whg_bf[i] = f2bf(Whg[i]); }
    if (i < 256) bias_cat[i] = (i < 128) ? b_W[i] : res_b[i - 128];
    if (i < n) hist[i] = 0;
}

// ---- h (fp32) -> h_bf (bf16), 8 elems/thread ----
__global__ __launch_bounds__(256) void k_cvt(const float* __restrict__ x,
    unsigned short* __restrict__ y, int n8)
{
    int i = blockIdx.x * 256 + threadIdx.x;
    if (i >= n8) return;
    float4 v0 = ((const float4*)x)[2 * i];
    float4 v1 = ((const float4*)x)[2 * i + 1];
    uint4 o;
    o.x = (unsigned int)f2bf(v0.x) | ((unsigned int)f2bf(v0.y) << 16);
    o.y = (unsigned int)f2bf(v0.z) | ((unsigned int)f2bf(v0.w) << 16);
    o.z = (unsigned int)f2bf(v1.x) | ((unsigned int)f2bf(v1.y) << 16);
    o.w = (unsigned int)f2bf(v1.z) | ((unsigned int)f2bf(v1.w) << 16);
    ((uint4*)y)[i] = o;
}

// ---- CSR build ----
__global__ void k_hist(const int* __restrict__ dstv, int* hist, int e) {
    int i = blockIdx.x * 256 + threadIdx.x;
    if (i < e) atomicAdd(&hist[dstv[i]], 1);
}
__global__ __launch_bounds__(1024) void k_scan(const int* __restrict__ hist,
    int* __restrict__ row_start, int* __restrict__ cursor, int n)
{
    __shared__ int sums[1024];
    const int t = threadIdx.x;
    const int per = (n + 1023) >> 10;
    const int lo = t * per;
    const int hi = min(lo + per, n);
    int s = 0;
    for (int i = lo; i < hi; ++i) s += hist[i];
    sums[t] = s;
    __syncthreads();
    for (int o = 1; o < 1024; o <<= 1) {
        int add = (t >= o) ? sums[t - o] : 0;
        __syncthreads();
        sums[t] += add;
        __syncthreads();
    }
    int run = sums[t] - s;
    for (int i = lo; i < hi; ++i) {
        row_start[i] = run;
        cursor[i] = run;
        run += hist[i];
    }
    if (hi == n && lo <= n) row_start[n] = run;
}
__global__ void k_place(const int* __restrict__ dstv, const int* __restrict__ srcv,
    int* cursor, int* esrc, int e)
{
    int i = blockIdx.x * 256 + threadIdx.x;
    if (i < e) {
        int p = atomicAdd(&cursor[dstv[i]], 1);
        esrc[p] = srcv[i];
    }
}

// ---- MFMA GEMM: [Wh | hres] = h_bf @ [W;res_W]^T + bias, bf16 out ----
// block = 4 waves, M=16 rows, each wave 64 cols of 256
__global__ __launch_bounds__(256) void k_whres(const unsigned short* __restrict__ h_bf,
    const unsigned short* __restrict__ Wcat, const float* __restrict__ bias_cat,
    unsigned short* __restrict__ Wh, unsigned short* __restrict__ hres, int n)
{
    const int t = threadIdx.x;
    const int w = t >> 6, l = t & 63;
    const int row0 = blockIdx.x * 16;
    const int colBase = w * 64;
    const int lr = l & 15;
    const int kg = (l >> 4) * 8;
    f32x4 acc[4] = {};
    const unsigned short* Ap = h_bf + (size_t)(row0 + lr) * 128 + kg;
    for (int ks = 0; ks < 4; ++ks) {
        bf16x8 a = *(const bf16x8*)(Ap + ks * 32);
#pragma unroll
        for (int nsub = 0; nsub < 4; ++nsub) {
            int j = colBase + nsub * 16 + lr;
            bf16x8 b = *(const bf16x8*)(Wcat + (size_t)j * 128 + ks * 32 + kg);
            acc[nsub] = __builtin_amdgcn_mfma_f32_16x16x32_bf16(a, b, acc[nsub], 0, 0, 0);
        }
    }
#pragma unroll
    for (int nsub = 0; nsub < 4; ++nsub) {
        int j = colBase + nsub * 16 + lr;
        float bj = bias_cat[j];
        unsigned short* dst = (j < 128) ? (Wh + j) : (hres + (j - 128));
#pragma unroll
        for (int r = 0; r < 4; ++r) {
            int i = row0 + (l >> 4) * 4 + r;
            if (i < n) dst[(size_t)i * 128] = f2bf(acc[nsub][r] + bj);
        }
    }
}

// ---- s_s = Wh.a_src, s_d = Wh.a_dst (1 wave / row, bf16 Wh) ----
__global__ __launch_bounds__(256) void k_ssd(const unsigned short* __restrict__ Wh,
    const float* __restrict__ a_src, const float* __restrict__ a_dst,
    float* __restrict__ s_s, float* __restrict__ s_d, int n)
{
    int wave = (int)((blockIdx.x * 256u + threadIdx.x) >> 6);
    int lane = threadIdx.x & 63;
    if (wave >= n) return;
    unsigned int v = *(const unsigned int*)(Wh + (size_t)wave * 128 + 2 * lane);
    float vx = bf2f((unsigned short)(v & 0xffff));
    float vy = bf2f((unsigned short)(v >> 16));
    float2 as = ((const float2*)a_src)[lane];
    float2 ad = ((const float2*)a_dst)[lane];
    float ps = vx * as.x + vy * as.y;
    float pd = vx * ad.x + vy * ad.y;
#pragma unroll
    for (int o = 32; o; o >>= 1) {
        ps += __shfl_down(ps, o);
        pd += __shfl_down(pd, o);
    }
    if (lane == 0) { s_s[wave] = ps; s_d[wave] = pd; }
}

// ---- fused segment softmax (no max pass) + weighted aggregation + residual add ----
__global__ __launch_bounds__(256) void k_attn(const int* __restrict__ row_start,
    const int* __restrict__ esrc, const float* __restrict__ s_s,
    const float* __restrict__ s_d, const float* __restrict__ a_b,
    const unsigned short* __restrict__ Wh, const unsigned short* __restrict__ hres,
    unsigned short* __restrict__ hp, int n)
{
    const int node = (int)((blockIdx.x * 256u + threadIdx.x) >> 6);
    const int l = threadIdx.x & 63;
    if (node >= n) return;
    const int lo = row_start[node], hi = row_start[node + 1];
    const float sdn = s_d[node] + a_b[0];

    float sv = 0.f, den = 0.f;
    for (int p = lo + l; p < hi; p += 64) {
        float ev = s_s[esrc[p]] + sdn;
        ev = ev > 0.f ? ev : NLALPHA * ev;
        float ex = expf(ev);
        if (p - lo < 64) sv = ex;
        den += ex;
    }
#pragma unroll
    for (int o = 32; o; o >>= 1) den += __shfl_xor(den, o);
    const float dinv = 1.f / (den > 0.f ? den : 1.f);

    const int cnt = hi - lo;
    float ax = 0.f, ay = 0.f;
    for (int q = 0; q < cnt; ++q) {
        int s = esrc[lo + q];
        float ex;
        if (q < 64) ex = __shfl(sv, q);
        else {
            float ev = s_s[s] + sdn;
            ev = ev > 0.f ? ev : NLALPHA * ev;
            ex = expf(ev);
        }
        float wgt = ex * dinv;
        unsigned int v = *(const unsigned int*)(Wh + (size_t)s * 128 + 2 * l);
        ax = fmaf(wgt, bf2f((unsigned short)(v & 0xffff)), ax);
        ay = fmaf(wgt, bf2f((unsigned short)(v >> 16)), ay);
    }
    unsigned int hv = *(const unsigned int*)(hres + (size_t)node * 128 + 2 * l);
    ax += bf2f((unsigned short)(hv & 0xffff));
    ay += bf2f((unsigned short)(hv >> 16));
    unsigned int o = (unsigned int)f2bf(ax) | ((unsigned int)f2bf(ay) << 16);
    *(unsigned int*)(hp + (size_t)node * 128 + 2 * l) = o;
}

// ---- fused GRU via MFMA: gi = hp@Wi^T, gh = h@Whg^T, gates, blend ----
// block = 4 waves, M=32 rows (2 msub), wave owns 32 output cols (2 nsub) across all 3 gates
__global__ __launch_bounds__(256) void k_gru(const unsigned short* __restrict__ hp_bf,
    const unsigned short* __restrict__ h_bf, const unsigned short* __restrict__ Wi_bf,
    const unsigned short* __restrict__ Whg_bf, const float* __restrict__ bi,
    const float* __restrict__ bh, const float* __restrict__ h,
    float* __restrict__ out, int n)
{
    const int t = threadIdx.x;
    const int w = t >> 6, l = t & 63;
    const int row0 = blockIdx.x * 32;
    const int j0 = w * 32;
    const int lr = l & 15;
    const int kg = (l >> 4) * 8;

    f32x4 gi[3][2][2] = {};
    f32x4 gh[3][2][2] = {};

    for (int ks = 0; ks < 4; ++ks) {
        bf16x8 aP[2], aH[2];
#pragma unroll
        for (int m = 0; m < 2; ++m) {
            size_t ra = (size_t)min(row0 + m * 16 + lr, n - 1) * 128 + ks * 32 + kg;
            aP[m] = *(const bf16x8*)(hp_bf + ra);
            aH[m] = *(const bf16x8*)(h_bf + ra);
        }
#pragma unroll
        for (int g = 0; g < 3; ++g) {
#pragma unroll
            for (int nsub = 0; nsub < 2; ++nsub) {
                int j = g * 128 + j0 + nsub * 16 + lr;
                bf16x8 bwi = *(const bf16x8*)(Wi_bf + (size_t)j * 128 + ks * 32 + kg);
                bf16x8 bwh = *(const bf16x8*)(Whg_bf + (size_t)j * 128 + ks * 32 + kg);
#pragma unroll
                for (int m = 0; m < 2; ++m) {
                    gi[g][m][nsub] = __builtin_amdgcn_mfma_f32_16x16x32_bf16(aP[m], bwi, gi[g][m][nsub], 0, 0, 0);
                    gh[g][m][nsub] = __builtin_amdgcn_mfma_f32_16x16x32_bf16(aH[m], bwh, gh[g][m][nsub], 0, 0, 0);
                }
            }
        }
    }

#pragma unroll
    for (int m = 0; m < 2; ++m) {
#pragma unroll
        for (int nsub = 0; nsub < 2; ++nsub) {
            int col = j0 + nsub * 16 + lr;
            float biR = bi[col], bhR = bh[col];
            float biZ = bi[128 + col], bhZ = bh[128 + col];
            float biN = bi[256 + col], bhN = bh[256 + col];
#pragma unroll
            for (int r = 0; r < 4; ++r) {
                int row = row0 + m * 16 + (l >> 4) * 4 + r;
                if (row < n) {
                    float rg = sigmoidf_(gi[0][m][nsub][r] + biR + gh[0][m][nsub][r] + bhR);
                    float zg = sigmoidf_(gi[1][m][nsub][r] + biZ + gh[1][m][nsub][r] + bhZ);
                    float ng = tanhf(gi[2][m][nsub][r] + biN + rg * (gh[2][m][nsub][r] + bhN));
                    float hv = h[(size_t)row * 128 + col];
                    out[(size_t)row * 128 + col] = (1.f - zg) * ng + zg * hv;
                }
            }
        }
    }
}

extern "C" void kernel_launch(void* const* d_in, const int* in_sizes, int n_in,
                              void* d_out, int out_size, void* d_ws, size_t ws_size,
                              hipStream_t stream)
{
    const float* h     = (const float*)d_in[0];
    const int*   srcv  = (const int*)d_in[1];
    const int*   dstv  = (const int*)d_in[2];
    const float* W     = (const float*)d_in[3];
    const float* b_W   = (const float*)d_in[4];
    const float* a_src = (const float*)d_in[5];
    const float* a_dst = (const float*)d_in[6];
    const float* a_b   = (const float*)d_in[7];
    const float* res_W = (const float*)d_in[8];
    const float* res_b = (const float*)d_in[9];
    const float* Wi    = (const float*)d_in[10];
    const float* Whg   = (const float*)d_in[11];
    const float* bi    = (const float*)d_in[12];
    const float* bh    = (const float*)d_in[13];
    float* out = (float*)d_out;
    const int n = in_sizes[0] / 128;
    const int e = in_sizes[1];

    char* p = (char*)d_ws;
    auto carve = [&](size_t bytes) -> char* {
        char* r = p;
        p += (bytes + 255) & ~(size_t)255;
        return r;
    };
    unsigned short* h_bf   = (unsigned short*)carve((size_t)n * 128 * 2);
    unsigned short* Wh     = (unsigned short*)carve((size_t)n * 128 * 2);
    unsigned short* hres   = (unsigned short*)carve((size_t)n * 128 * 2);
    unsigned short* hp_bf  = (unsigned short*)carve((size_t)n * 128 * 2);
    float* s_s             = (float*)carve((size_t)n * 4);
    float* s_d             = (float*)carve((size_t)n * 4);
    int*   hist            = (int*)carve((size_t)n * 4);
    int*   row_start       = (int*)carve((size_t)(n + 1) * 4);
    int*   cursor          = (int*)carve((size_t)n * 4);
    int*   esrc            = (int*)carve((size_t)e * 4);
    unsigned short* Wcat   = (unsigned short*)carve(32768 * 2);
    unsigned short* Wi_bf  = (unsigned short*)carve(49152 * 2);
    unsigned short* Whg_bf = (unsigned short*)carve(49152 * 2);
    float* bias_cat        = (float*)carve(256 * 4);

    k_prep<<<192, 256, 0, stream>>>(W, res_W, b_W, res_b, Wi, Whg,
                                    Wcat, Wi_bf, Whg_bf, bias_cat, hist, n);
    k_cvt<<<(n * 16 + 255) / 256, 256, 0, stream>>>(h, h_bf, n * 16);
    k_hist<<<(e + 255) / 256, 256, 0, stream>>>(dstv, hist, e);
    k_scan<<<1, 1024, 0, stream>>>(hist, row_start, cursor, n);
    k_place<<<(e + 255) / 256, 256, 0, stream>>>(dstv, srcv, cursor, esrc, e);
    k_whres<<<(n + 15) / 16, 256, 0, stream>>>(h_bf, Wcat, bias_cat, Wh, hres, n);
    k_ssd<<<((size_t)n * 64 + 255) / 256, 256, 0, stream>>>(Wh, a_src, a_dst, s_s, s_d, n);
    k_attn<<<((size_t)n * 64 + 255) / 256, 256, 0, stream>>>(row_start, esrc, s_s, s_d, a_b, Wh, hres, hp_bf, n);
    k_gru<<<(n + 31) / 32, 256, 0, stream>>>(hp_bf, h_bf, Wi_bf, Whg_bf, bi, bh, h, out, n);
}

// Round 3
// 239.673 us; speedup vs baseline: 4.2054x; 1.3625x over previous
//
#include <hip/hip_runtime.h>
#include <math.h>

#define NLALPHA 0.2f

typedef __attribute__((ext_vector_type(8))) short bf16x8;
typedef __attribute__((ext_vector_type(4))) float f32x4;

static __device__ __forceinline__ float sigmoidf_(float x) { return 1.f / (1.f + expf(-x)); }
static __device__ __forceinline__ unsigned short f2bf(float f) {
    unsigned int u = __float_as_uint(f);
    return (unsigned short)((u + 0x7fffu + ((u >> 16) & 1u)) >> 16);
}
static __device__ __forceinline__ float bf2f(unsigned short b) {
    return __uint_as_float(((unsigned int)b) << 16);
}

// ---- prep (grid covers n*16): h->bf16, weights->bf16, concat biases, zero hist ----
__global__ __launch_bounds__(256) void k_prep(const float* __restrict__ h,
    const float* __restrict__ W, const float* __restrict__ res_W,
    const float* __restrict__ b_W, const float* __restrict__ res_b,
    const float* __restrict__ Wi, const float* __restrict__ Whg,
    unsigned short* __restrict__ h_bf, unsigned short* __restrict__ Wcat,
    unsigned short* __restrict__ Wi_bf, unsigned short* __restrict__ Whg_bf,
    float* __restrict__ bias_cat, int* __restrict__ hist, int n)
{
    int i = blockIdx.x * 256 + threadIdx.x;
    if (i < n * 16) {   // 8 elems/thread h conversion
        float4 v0 = ((const float4*)h)[2 * i];
        float4 v1 = ((const float4*)h)[2 * i + 1];
        uint4 o;
        o.x = (unsigned int)f2bf(v0.x) | ((unsigned int)f2bf(v0.y) << 16);
        o.y = (unsigned int)f2bf(v0.z) | ((unsigned int)f2bf(v0.w) << 16);
        o.z = (unsigned int)f2bf(v1.x) | ((unsigned int)f2bf(v1.y) << 16);
        o.w = (unsigned int)f2bf(v1.z) | ((unsigned int)f2bf(v1.w) << 16);
        ((uint4*)h_bf)[i] = o;
    }
    if (i < 32768) Wcat[i] = f2bf(i < 16384 ? W[i] : res_W[i - 16384]);
    if (i < 49152) { Wi_bf[i] = f2bf(Wi[i]); Whg_bf[i] = f2bf(Whg[i]); }
    if (i < 256) bias_cat[i] = (i < 128) ? b_W[i] : res_b[i - 128];
    if (i < n) hist[i] = 0;
}

// ---- CSR build ----
__global__ void k_hist(const int* __restrict__ dstv, int* hist, int e) {
    int i = blockIdx.x * 256 + threadIdx.x;
    if (i < e) atomicAdd(&hist[dstv[i]], 1);
}
// hierarchical scan: block sums -> scan sums -> per-block scan with base
__global__ __launch_bounds__(256) void k_bsum(const int* __restrict__ hist,
    int* __restrict__ bsum, int n)
{
    int i = blockIdx.x * 256 + threadIdx.x;
    int v = (i < n) ? hist[i] : 0;
#pragma unroll
    for (int o = 32; o; o >>= 1) v += __shfl_down(v, o);
    __shared__ int ws[4];
    if ((threadIdx.x & 63) == 0) ws[threadIdx.x >> 6] = v;
    __syncthreads();
    if (threadIdx.x == 0) bsum[blockIdx.x] = ws[0] + ws[1] + ws[2] + ws[3];
}
__global__ __launch_bounds__(256) void k_bscan(int* __restrict__ bsum, int nb)
{
    __shared__ int s[256];
    int t = threadIdx.x;
    int v = (t < nb) ? bsum[t] : 0;
    s[t] = v;
    __syncthreads();
    for (int o = 1; o < 256; o <<= 1) {
        int a = (t >= o) ? s[t - o] : 0;
        __syncthreads();
        s[t] += a;
        __syncthreads();
    }
    if (t < nb) bsum[t] = s[t] - v;   // exclusive
}
__global__ __launch_bounds__(256) void k_scan3(const int* __restrict__ hist,
    const int* __restrict__ bsum, int* __restrict__ row_start,
    int* __restrict__ cursor, int n, int e)
{
    int b = blockIdx.x, t = threadIdx.x;
    int i = b * 256 + t;
    int v = (i < n) ? hist[i] : 0;
    __shared__ int s[256];
    s[t] = v;
    __syncthreads();
    for (int o = 1; o < 256; o <<= 1) {
        int a = (t >= o) ? s[t - o] : 0;
        __syncthreads();
        s[t] += a;
        __syncthreads();
    }
    int ex = s[t] - v + bsum[b];
    if (i < n) { row_start[i] = ex; cursor[i] = ex; }
    if (i == 0) row_start[n] = e;
}
__global__ void k_place(const int* __restrict__ dstv, const int* __restrict__ srcv,
    int* cursor, int* esrc, int e)
{
    int i = blockIdx.x * 256 + threadIdx.x;
    if (i < e) {
        int p = atomicAdd(&cursor[dstv[i]], 1);
        esrc[p] = srcv[i];
    }
}

// ---- MFMA GEMM: [Wh | hres] = h_bf @ [W;res_W]^T + bias, bf16 out ----
__global__ __launch_bounds__(256) void k_whres(const unsigned short* __restrict__ h_bf,
    const unsigned short* __restrict__ Wcat, const float* __restrict__ bias_cat,
    unsigned short* __restrict__ Wh, unsigned short* __restrict__ hres, int n)
{
    const int t = threadIdx.x;
    const int w = t >> 6, l = t & 63;
    const int row0 = blockIdx.x * 16;
    const int colBase = w * 64;
    const int lr = l & 15;
    const int kg = (l >> 4) * 8;
    f32x4 acc[4] = {};
    const unsigned short* Ap = h_bf + (size_t)(row0 + lr) * 128 + kg;
    for (int ks = 0; ks < 4; ++ks) {
        bf16x8 a = *(const bf16x8*)(Ap + ks * 32);
#pragma unroll
        for (int nsub = 0; nsub < 4; ++nsub) {
            int j = colBase + nsub * 16 + lr;
            bf16x8 b = *(const bf16x8*)(Wcat + (size_t)j * 128 + ks * 32 + kg);
            acc[nsub] = __builtin_amdgcn_mfma_f32_16x16x32_bf16(a, b, acc[nsub], 0, 0, 0);
        }
    }
#pragma unroll
    for (int nsub = 0; nsub < 4; ++nsub) {
        int j = colBase + nsub * 16 + lr;
        float bj = bias_cat[j];
        unsigned short* dst = (j < 128) ? (Wh + j) : (hres + (j - 128));
#pragma unroll
        for (int r = 0; r < 4; ++r) {
            int i = row0 + (l >> 4) * 4 + r;
            if (i < n) dst[(size_t)i * 128] = f2bf(acc[nsub][r] + bj);
        }
    }
}

// ---- s_s = Wh.a_src, s_d = Wh.a_dst (1 wave / row, bf16 Wh) ----
__global__ __launch_bounds__(256) void k_ssd(const unsigned short* __restrict__ Wh,
    const float* __restrict__ a_src, const float* __restrict__ a_dst,
    float* __restrict__ s_s, float* __restrict__ s_d, int n)
{
    int wave = (int)((blockIdx.x * 256u + threadIdx.x) >> 6);
    int lane = threadIdx.x & 63;
    if (wave >= n) return;
    unsigned int v = *(const unsigned int*)(Wh + (size_t)wave * 128 + 2 * lane);
    float vx = bf2f((unsigned short)(v & 0xffff));
    float vy = bf2f((unsigned short)(v >> 16));
    float2 as = ((const float2*)a_src)[lane];
    float2 ad = ((const float2*)a_dst)[lane];
    float ps = vx * as.x + vy * as.y;
    float pd = vx * ad.x + vy * ad.y;
#pragma unroll
    for (int o = 32; o; o >>= 1) {
        ps += __shfl_down(ps, o);
        pd += __shfl_down(pd, o);
    }
    if (lane == 0) { s_s[wave] = ps; s_d[wave] = pd; }
}

// ---- fused segment softmax (no max pass) + weighted aggregation + residual add ----
__global__ __launch_bounds__(256) void k_attn(const int* __restrict__ row_start,
    const int* __restrict__ esrc, const float* __restrict__ s_s,
    const float* __restrict__ s_d, const float* __restrict__ a_b,
    const unsigned short* __restrict__ Wh, const unsigned short* __restrict__ hres,
    unsigned short* __restrict__ hp, int n)
{
    const int node = (int)((blockIdx.x * 256u + threadIdx.x) >> 6);
    const int l = threadIdx.x & 63;
    if (node >= n) return;
    const int lo = row_start[node], hi = row_start[node + 1];
    const float sdn = s_d[node] + a_b[0];

    float sv = 0.f, den = 0.f;
    for (int p = lo + l; p < hi; p += 64) {
        float ev = s_s[esrc[p]] + sdn;
        ev = ev > 0.f ? ev : NLALPHA * ev;
        float ex = expf(ev);
        if (p - lo < 64) sv = ex;
        den += ex;
    }
#pragma unroll
    for (int o = 32; o; o >>= 1) den += __shfl_xor(den, o);
    const float dinv = 1.f / (den > 0.f ? den : 1.f);

    const int cnt = hi - lo;
    float ax = 0.f, ay = 0.f;
    for (int q = 0; q < cnt; ++q) {
        int s = esrc[lo + q];
        float ex;
        if (q < 64) ex = __shfl(sv, q);
        else {
            float ev = s_s[s] + sdn;
            ev = ev > 0.f ? ev : NLALPHA * ev;
            ex = expf(ev);
        }
        float wgt = ex * dinv;
        unsigned int v = *(const unsigned int*)(Wh + (size_t)s * 128 + 2 * l);
        ax = fmaf(wgt, bf2f((unsigned short)(v & 0xffff)), ax);
        ay = fmaf(wgt, bf2f((unsigned short)(v >> 16)), ay);
    }
    unsigned int hv = *(const unsigned int*)(hres + (size_t)node * 128 + 2 * l);
    ax += bf2f((unsigned short)(hv & 0xffff));
    ay += bf2f((unsigned short)(hv >> 16));
    unsigned int o = (unsigned int)f2bf(ax) | ((unsigned int)f2bf(ay) << 16);
    *(unsigned int*)(hp + (size_t)node * 128 + 2 * l) = o;
}

// ---- fused GRU via MFMA ----
__global__ __launch_bounds__(256) void k_gru(const unsigned short* __restrict__ hp_bf,
    const unsigned short* __restrict__ h_bf, const unsigned short* __restrict__ Wi_bf,
    const unsigned short* __restrict__ Whg_bf, const float* __restrict__ bi,
    const float* __restrict__ bh, const float* __restrict__ h,
    float* __restrict__ out, int n)
{
    const int t = threadIdx.x;
    const int w = t >> 6, l = t & 63;
    const int row0 = blockIdx.x * 32;
    const int j0 = w * 32;
    const int lr = l & 15;
    const int kg = (l >> 4) * 8;

    f32x4 gi[3][2][2] = {};
    f32x4 gh[3][2][2] = {};

    for (int ks = 0; ks < 4; ++ks) {
        bf16x8 aP[2], aH[2];
#pragma unroll
        for (int m = 0; m < 2; ++m) {
            size_t ra = (size_t)min(row0 + m * 16 + lr, n - 1) * 128 + ks * 32 + kg;
            aP[m] = *(const bf16x8*)(hp_bf + ra);
            aH[m] = *(const bf16x8*)(h_bf + ra);
        }
#pragma unroll
        for (int g = 0; g < 3; ++g) {
#pragma unroll
            for (int nsub = 0; nsub < 2; ++nsub) {
                int j = g * 128 + j0 + nsub * 16 + lr;
                bf16x8 bwi = *(const bf16x8*)(Wi_bf + (size_t)j * 128 + ks * 32 + kg);
                bf16x8 bwh = *(const bf16x8*)(Whg_bf + (size_t)j * 128 + ks * 32 + kg);
#pragma unroll
                for (int m = 0; m < 2; ++m) {
                    gi[g][m][nsub] = __builtin_amdgcn_mfma_f32_16x16x32_bf16(aP[m], bwi, gi[g][m][nsub], 0, 0, 0);
                    gh[g][m][nsub] = __builtin_amdgcn_mfma_f32_16x16x32_bf16(aH[m], bwh, gh[g][m][nsub], 0, 0, 0);
                }
            }
        }
    }

#pragma unroll
    for (int m = 0; m < 2; ++m) {
#pragma unroll
        for (int nsub = 0; nsub < 2; ++nsub) {
            int col = j0 + nsub * 16 + lr;
            float biR = bi[col], bhR = bh[col];
            float biZ = bi[128 + col], bhZ = bh[128 + col];
            float biN = bi[256 + col], bhN = bh[256 + col];
#pragma unroll
            for (int r = 0; r < 4; ++r) {
                int row = row0 + m * 16 + (l >> 4) * 4 + r;
                if (row < n) {
                    float rg = sigmoidf_(gi[0][m][nsub][r] + biR + gh[0][m][nsub][r] + bhR);
                    float zg = sigmoidf_(gi[1][m][nsub][r] + biZ + gh[1][m][nsub][r] + bhZ);
                    float ng = tanhf(gi[2][m][nsub][r] + biN + rg * (gh[2][m][nsub][r] + bhN));
                    float hv = h[(size_t)row * 128 + col];
                    out[(size_t)row * 128 + col] = (1.f - zg) * ng + zg * hv;
                }
            }
        }
    }
}

extern "C" void kernel_launch(void* const* d_in, const int* in_sizes, int n_in,
                              void* d_out, int out_size, void* d_ws, size_t ws_size,
                              hipStream_t stream)
{
    const float* h     = (const float*)d_in[0];
    const int*   srcv  = (const int*)d_in[1];
    const int*   dstv  = (const int*)d_in[2];
    const float* W     = (const float*)d_in[3];
    const float* b_W   = (const float*)d_in[4];
    const float* a_src = (const float*)d_in[5];
    const float* a_dst = (const float*)d_in[6];
    const float* a_b   = (const float*)d_in[7];
    const float* res_W = (const float*)d_in[8];
    const float* res_b = (const float*)d_in[9];
    const float* Wi    = (const float*)d_in[10];
    const float* Whg   = (const float*)d_in[11];
    const float* bi    = (const float*)d_in[12];
    const float* bh    = (const float*)d_in[13];
    float* out = (float*)d_out;
    const int n = in_sizes[0] / 128;
    const int e = in_sizes[1];
    const int nb = (n + 255) / 256;

    char* p = (char*)d_ws;
    auto carve = [&](size_t bytes) -> char* {
        char* r = p;
        p += (bytes + 255) & ~(size_t)255;
        return r;
    };
    unsigned short* h_bf   = (unsigned short*)carve((size_t)n * 128 * 2);
    unsigned short* Wh     = (unsigned short*)carve((size_t)n * 128 * 2);
    unsigned short* hres   = (unsigned short*)carve((size_t)n * 128 * 2);
    unsigned short* hp_bf  = (unsigned short*)carve((size_t)n * 128 * 2);
    float* s_s             = (float*)carve((size_t)n * 4);
    float* s_d             = (float*)carve((size_t)n * 4);
    int*   hist            = (int*)carve((size_t)n * 4);
    int*   row_start       = (int*)carve((size_t)(n + 1) * 4);
    int*   cursor          = (int*)carve((size_t)n * 4);
    int*   esrc            = (int*)carve((size_t)e * 4);
    int*   bsum            = (int*)carve((size_t)nb * 4);
    unsigned short* Wcat   = (unsigned short*)carve(32768 * 2);
    unsigned short* Wi_bf  = (unsigned short*)carve(49152 * 2);
    unsigned short* Whg_bf = (unsigned short*)carve(49152 * 2);
    float* bias_cat        = (float*)carve(256 * 4);

    k_prep<<<(n * 16 + 255) / 256, 256, 0, stream>>>(h, W, res_W, b_W, res_b, Wi, Whg,
                                    h_bf, Wcat, Wi_bf, Whg_bf, bias_cat, hist, n);
    k_hist<<<(e + 255) / 256, 256, 0, stream>>>(dstv, hist, e);
    k_bsum<<<nb, 256, 0, stream>>>(hist, bsum, n);
    k_bscan<<<1, 256, 0, stream>>>(bsum, nb);
    k_scan3<<<nb, 256, 0, stream>>>(hist, bsum, row_start, cursor, n, e);
    k_place<<<(e + 255) / 256, 256, 0, stream>>>(dstv, srcv, cursor, esrc, e);
    k_whres<<<(n + 15) / 16, 256, 0, stream>>>(h_bf, Wcat, bias_cat, Wh, hres, n);
    k_ssd<<<((size_t)n * 64 + 255) / 256, 256, 0, stream>>>(Wh, a_src, a_dst, s_s, s_d, n);
    k_attn<<<((size_t)n * 64 + 255) / 256, 256, 0, stream>>>(row_start, esrc, s_s, s_d, a_b, Wh, hres, hp_bf, n);
    k_gru<<<(n + 31) / 32, 256, 0, stream>>>(hp_bf, h_bf, Wi_bf, Whg_bf, bi, bh, h, out, n);
}

// Round 4
// 195.096 us; speedup vs baseline: 5.1663x; 1.2285x over previous
//
#include <hip/hip_runtime.h>
#include <math.h>

#define NLALPHA 0.2f

typedef __attribute__((ext_vector_type(8))) short bf16x8;
typedef __attribute__((ext_vector_type(4))) float f32x4;

static __device__ __forceinline__ float sigmoidf_(float x) { return 1.f / (1.f + expf(-x)); }
static __device__ __forceinline__ unsigned short f2bf(float f) {
    unsigned int u = __float_as_uint(f);
    return (unsigned short)((u + 0x7fffu + ((u >> 16) & 1u)) >> 16);
}
static __device__ __forceinline__ float bf2f(unsigned short b) {
    return __uint_as_float(((unsigned int)b) << 16);
}

// ---- va = W^T a_src / W^T a_dst, c = b_W.a ----
__global__ __launch_bounds__(128) void k_va(const float* __restrict__ W,
    const float* __restrict__ a_src, const float* __restrict__ a_dst,
    const float* __restrict__ b_W, float* __restrict__ va, float* __restrict__ cc)
{
    int k = threadIdx.x;
    float ss = 0.f, dd = 0.f;
    for (int j = 0; j < 128; ++j) {
        float w = W[j * 128 + k];
        ss = fmaf(w, a_src[j], ss);
        dd = fmaf(w, a_dst[j], dd);
    }
    va[k] = ss;
    va[128 + k] = dd;
    float cs = b_W[k] * a_src[k], cd = b_W[k] * a_dst[k];
#pragma unroll
    for (int o = 32; o; o >>= 1) { cs += __shfl_down(cs, o); cd += __shfl_down(cd, o); }
    __shared__ float sh[4];
    if ((k & 63) == 0) { sh[(k >> 6) * 2] = cs; sh[(k >> 6) * 2 + 1] = cd; }
    __syncthreads();
    if (k == 0) { cc[0] = sh[0] + sh[2]; cc[1] = sh[1] + sh[3]; }
}

// ---- prep: h->bf16 + s_s/s_d inline, weights->bf16, biases, zero hist ----
__global__ __launch_bounds__(256) void k_prep(const float* __restrict__ h,
    const float* __restrict__ W, const float* __restrict__ res_W,
    const float* __restrict__ b_W, const float* __restrict__ res_b,
    const float* __restrict__ Wi, const float* __restrict__ Whg,
    const float* __restrict__ va, const float* __restrict__ cc,
    unsigned short* __restrict__ h_bf, unsigned short* __restrict__ Wcat,
    unsigned short* __restrict__ Wi_bf, unsigned short* __restrict__ Whg_bf,
    float* __restrict__ bias_cat, float* __restrict__ s_s, float* __restrict__ s_d,
    int* __restrict__ hist, int n)
{
    int i = blockIdx.x * 256 + threadIdx.x;
    int t = threadIdx.x;
    if (i < n * 16) {   // 8 elems/thread; 16 threads cover one row
        float4 v0 = ((const float4*)h)[2 * i];
        float4 v1 = ((const float4*)h)[2 * i + 1];
        uint4 o;
        o.x = (unsigned int)f2bf(v0.x) | ((unsigned int)f2bf(v0.y) << 16);
        o.y = (unsigned int)f2bf(v0.z) | ((unsigned int)f2bf(v0.w) << 16);
        o.z = (unsigned int)f2bf(v1.x) | ((unsigned int)f2bf(v1.y) << 16);
        o.w = (unsigned int)f2bf(v1.z) | ((unsigned int)f2bf(v1.w) << 16);
        ((uint4*)h_bf)[i] = o;
        // s_s/s_d partials: cols (t&15)*8 .. +7
        const float* vs = va + (t & 15) * 8;
        const float* vd = vs + 128;
        float ps = v0.x*vs[0] + v0.y*vs[1] + v0.z*vs[2] + v0.w*vs[3]
                 + v1.x*vs[4] + v1.y*vs[5] + v1.z*vs[6] + v1.w*vs[7];
        float pd = v0.x*vd[0] + v0.y*vd[1] + v0.z*vd[2] + v0.w*vd[3]
                 + v1.x*vd[4] + v1.y*vd[5] + v1.z*vd[6] + v1.w*vd[7];
#pragma unroll
        for (int o2 = 1; o2 < 16; o2 <<= 1) {
            ps += __shfl_xor(ps, o2);
            pd += __shfl_xor(pd, o2);
        }
        if ((t & 15) == 0) {
            int row = i >> 4;
            s_s[row] = ps + cc[0];
            s_d[row] = pd + cc[1];
        }
    }
    if (i < 32768) Wcat[i] = f2bf(i < 16384 ? W[i] : res_W[i - 16384]);
    if (i < 49152) { Wi_bf[i] = f2bf(Wi[i]); Whg_bf[i] = f2bf(Whg[i]); }
    if (i < 256) bias_cat[i] = (i < 128) ? b_W[i] : res_b[i - 128];
    if (i < n) hist[i] = 0;
}

// ---- CSR build ----
__global__ void k_hist(const int* __restrict__ dstv, int* hist, int e) {
    int i = blockIdx.x * 256 + threadIdx.x;
    if (i < e) atomicAdd(&hist[dstv[i]], 1);
}
__global__ __launch_bounds__(256) void k_bsum(const int* __restrict__ hist,
    int* __restrict__ bsum, int n)
{
    int i = blockIdx.x * 256 + threadIdx.x;
    int v = (i < n) ? hist[i] : 0;
#pragma unroll
    for (int o = 32; o; o >>= 1) v += __shfl_down(v, o);
    __shared__ int ws[4];
    if ((threadIdx.x & 63) == 0) ws[threadIdx.x >> 6] = v;
    __syncthreads();
    if (threadIdx.x == 0) bsum[blockIdx.x] = ws[0] + ws[1] + ws[2] + ws[3];
}
__global__ __launch_bounds__(256) void k_bscan(int* __restrict__ bsum, int nb)
{
    __shared__ int s[256];
    int t = threadIdx.x;
    int v = (t < nb) ? bsum[t] : 0;
    s[t] = v;
    __syncthreads();
    for (int o = 1; o < 256; o <<= 1) {
        int a = (t >= o) ? s[t - o] : 0;
        __syncthreads();
        s[t] += a;
        __syncthreads();
    }
    if (t < nb) bsum[t] = s[t] - v;
}
__global__ __launch_bounds__(256) void k_scan3(const int* __restrict__ hist,
    const int* __restrict__ bsum, int* __restrict__ row_start,
    int* __restrict__ cursor, int n, int e)
{
    int b = blockIdx.x, t = threadIdx.x;
    int i = b * 256 + t;
    int v = (i < n) ? hist[i] : 0;
    __shared__ int s[256];
    s[t] = v;
    __syncthreads();
    for (int o = 1; o < 256; o <<= 1) {
        int a = (t >= o) ? s[t - o] : 0;
        __syncthreads();
        s[t] += a;
        __syncthreads();
    }
    int ex = s[t] - v + bsum[b];
    if (i < n) { row_start[i] = ex; cursor[i] = ex; }
    if (i == 0) row_start[n] = e;
}
__global__ void k_place(const int* __restrict__ dstv, const int* __restrict__ srcv,
    int* cursor, int* esrc, int e)
{
    int i = blockIdx.x * 256 + threadIdx.x;
    if (i < e) {
        int p = atomicAdd(&cursor[dstv[i]], 1);
        esrc[p] = srcv[i];
    }
}

// ---- MFMA GEMM: [Wh | hres] = h_bf @ [W;res_W]^T + bias, bf16 out, M=32 ----
__global__ __launch_bounds__(256) void k_whres(const unsigned short* __restrict__ h_bf,
    const unsigned short* __restrict__ Wcat, const float* __restrict__ bias_cat,
    unsigned short* __restrict__ Wh, unsigned short* __restrict__ hres, int n)
{
    const int t = threadIdx.x;
    const int w = t >> 6, l = t & 63;
    const int row0 = blockIdx.x * 32;
    const int colBase = w * 64;
    const int lr = l & 15;
    const int kg = (l >> 4) * 8;
    f32x4 acc[2][4] = {};
    for (int ks = 0; ks < 4; ++ks) {
        bf16x8 a0 = *(const bf16x8*)(h_bf + (size_t)min(row0 + lr, n - 1) * 128 + ks * 32 + kg);
        bf16x8 a1 = *(const bf16x8*)(h_bf + (size_t)min(row0 + 16 + lr, n - 1) * 128 + ks * 32 + kg);
#pragma unroll
        for (int nsub = 0; nsub < 4; ++nsub) {
            int j = colBase + nsub * 16 + lr;
            bf16x8 b = *(const bf16x8*)(Wcat + (size_t)j * 128 + ks * 32 + kg);
            acc[0][nsub] = __builtin_amdgcn_mfma_f32_16x16x32_bf16(a0, b, acc[0][nsub], 0, 0, 0);
            acc[1][nsub] = __builtin_amdgcn_mfma_f32_16x16x32_bf16(a1, b, acc[1][nsub], 0, 0, 0);
        }
    }
#pragma unroll
    for (int nsub = 0; nsub < 4; ++nsub) {
        int j = colBase + nsub * 16 + lr;
        float bj = bias_cat[j];
        unsigned short* dst = (j < 128) ? (Wh + j) : (hres + (j - 128));
#pragma unroll
        for (int m = 0; m < 2; ++m) {
#pragma unroll
            for (int r = 0; r < 4; ++r) {
                int i = row0 + m * 16 + (l >> 4) * 4 + r;
                if (i < n) dst[(size_t)i * 128] = f2bf(acc[m][nsub][r] + bj);
            }
        }
    }
}

// ---- fused segment softmax + aggregation (4 edges/iter) + residual ----
__global__ __launch_bounds__(256) void k_attn(const int* __restrict__ row_start,
    const int* __restrict__ esrc, const float* __restrict__ s_s,
    const float* __restrict__ s_d, const float* __restrict__ a_b,
    const unsigned short* __restrict__ Wh, const unsigned short* __restrict__ hres,
    unsigned short* __restrict__ hp, int n)
{
    const int node = (int)((blockIdx.x * 256u + threadIdx.x) >> 6);
    const int l = threadIdx.x & 63;
    if (node >= n) return;
    const int lo = row_start[node], hi = row_start[node + 1];
    const int cnt = hi - lo;
    const float sdn = s_d[node] + a_b[0];
    const int g = l >> 4;      // edge subgroup
    const int c = l & 15;      // col group: cols c*8..c*8+7

    // pass 1: per-lane edge exp (+src cache) and denom
    float sv = 0.f;
    int ssrc = 0;
    float den = 0.f;
    for (int p = lo + l; p < hi; p += 64) {
        int s = esrc[p];
        float ev = s_s[s] + sdn;
        ev = ev > 0.f ? ev : NLALPHA * ev;
        float ex = expf(ev);
        if (p - lo < 64) { sv = ex; ssrc = s; }
        den += ex;
    }
#pragma unroll
    for (int o = 32; o; o >>= 1) den += __shfl_xor(den, o);
    const float dinv = 1.f / (den > 0.f ? den : 1.f);

    float acc[8] = {};
    const int q1 = min(cnt, 64);
    for (int q = 0; q < q1; q += 4) {
        int eix = q + g;
        bool valid = eix < cnt;
        int eic = valid ? eix : (cnt - 1);
        float ex = __shfl(sv, eic);
        int s = __shfl(ssrc, eic);
        float wgt = valid ? ex * dinv : 0.f;
        uint4 v = *(const uint4*)(Wh + (size_t)s * 128 + c * 8);
        acc[0] = fmaf(wgt, bf2f((unsigned short)(v.x & 0xffff)), acc[0]);
        acc[1] = fmaf(wgt, bf2f((unsigned short)(v.x >> 16)), acc[1]);
        acc[2] = fmaf(wgt, bf2f((unsigned short)(v.y & 0xffff)), acc[2]);
        acc[3] = fmaf(wgt, bf2f((unsigned short)(v.y >> 16)), acc[3]);
        acc[4] = fmaf(wgt, bf2f((unsigned short)(v.z & 0xffff)), acc[4]);
        acc[5] = fmaf(wgt, bf2f((unsigned short)(v.z >> 16)), acc[5]);
        acc[6] = fmaf(wgt, bf2f((unsigned short)(v.w & 0xffff)), acc[6]);
        acc[7] = fmaf(wgt, bf2f((unsigned short)(v.w >> 16)), acc[7]);
    }
    for (int q = 64; q < cnt; q += 4) {   // rare tail (deg > 64)
        int eix = q + g;
        bool valid = eix < cnt;
        int eic = valid ? eix : (cnt - 1);
        int s = esrc[lo + eic];
        float ev = s_s[s] + sdn;
        ev = ev > 0.f ? ev : NLALPHA * ev;
        float wgt = valid ? expf(ev) * dinv : 0.f;
        uint4 v = *(const uint4*)(Wh + (size_t)s * 128 + c * 8);
        acc[0] = fmaf(wgt, bf2f((unsigned short)(v.x & 0xffff)), acc[0]);
        acc[1] = fmaf(wgt, bf2f((unsigned short)(v.x >> 16)), acc[1]);
        acc[2] = fmaf(wgt, bf2f((unsigned short)(v.y & 0xffff)), acc[2]);
        acc[3] = fmaf(wgt, bf2f((unsigned short)(v.y >> 16)), acc[3]);
        acc[4] = fmaf(wgt, bf2f((unsigned short)(v.z & 0xffff)), acc[4]);
        acc[5] = fmaf(wgt, bf2f((unsigned short)(v.z >> 16)), acc[5]);
        acc[6] = fmaf(wgt, bf2f((unsigned short)(v.w & 0xffff)), acc[6]);
        acc[7] = fmaf(wgt, bf2f((unsigned short)(v.w >> 16)), acc[7]);
    }
#pragma unroll
    for (int k = 0; k < 8; ++k) {
        acc[k] += __shfl_xor(acc[k], 16);
        acc[k] += __shfl_xor(acc[k], 32);
    }
    if (l < 16) {
        uint4 hv = *(const uint4*)(hres + (size_t)node * 128 + l * 8);
        uint4 o;
        o.x = (unsigned int)f2bf(acc[0] + bf2f((unsigned short)(hv.x & 0xffff)))
            | ((unsigned int)f2bf(acc[1] + bf2f((unsigned short)(hv.x >> 16))) << 16);
        o.y = (unsigned int)f2bf(acc[2] + bf2f((unsigned short)(hv.y & 0xffff)))
            | ((unsigned int)f2bf(acc[3] + bf2f((unsigned short)(hv.y >> 16))) << 16);
        o.z = (unsigned int)f2bf(acc[4] + bf2f((unsigned short)(hv.z & 0xffff)))
            | ((unsigned int)f2bf(acc[5] + bf2f((unsigned short)(hv.z >> 16))) << 16);
        o.w = (unsigned int)f2bf(acc[6] + bf2f((unsigned short)(hv.w & 0xffff)))
            | ((unsigned int)f2bf(acc[7] + bf2f((unsigned short)(hv.w >> 16))) << 16);
        *(uint4*)(hp + (size_t)node * 128 + l * 8) = o;
    }
}

// ---- fused GRU via MFMA ----
__global__ __launch_bounds__(256) void k_gru(const unsigned short* __restrict__ hp_bf,
    const unsigned short* __restrict__ h_bf, const unsigned short* __restrict__ Wi_bf,
    const unsigned short* __restrict__ Whg_bf, const float* __restrict__ bi,
    const float* __restrict__ bh, const float* __restrict__ h,
    float* __restrict__ out, int n)
{
    const int t = threadIdx.x;
    const int w = t >> 6, l = t & 63;
    const int row0 = blockIdx.x * 32;
    const int j0 = w * 32;
    const int lr = l & 15;
    const int kg = (l >> 4) * 8;

    f32x4 gi[3][2][2] = {};
    f32x4 gh[3][2][2] = {};

    for (int ks = 0; ks < 4; ++ks) {
        bf16x8 aP[2], aH[2];
#pragma unroll
        for (int m = 0; m < 2; ++m) {
            size_t ra = (size_t)min(row0 + m * 16 + lr, n - 1) * 128 + ks * 32 + kg;
            aP[m] = *(const bf16x8*)(hp_bf + ra);
            aH[m] = *(const bf16x8*)(h_bf + ra);
        }
#pragma unroll
        for (int g = 0; g < 3; ++g) {
#pragma unroll
            for (int nsub = 0; nsub < 2; ++nsub) {
                int j = g * 128 + j0 + nsub * 16 + lr;
                bf16x8 bwi = *(const bf16x8*)(Wi_bf + (size_t)j * 128 + ks * 32 + kg);
                bf16x8 bwh = *(const bf16x8*)(Whg_bf + (size_t)j * 128 + ks * 32 + kg);
#pragma unroll
                for (int m = 0; m < 2; ++m) {
                    gi[g][m][nsub] = __builtin_amdgcn_mfma_f32_16x16x32_bf16(aP[m], bwi, gi[g][m][nsub], 0, 0, 0);
                    gh[g][m][nsub] = __builtin_amdgcn_mfma_f32_16x16x32_bf16(aH[m], bwh, gh[g][m][nsub], 0, 0, 0);
                }
            }
        }
    }

#pragma unroll
    for (int m = 0; m < 2; ++m) {
#pragma unroll
        for (int nsub = 0; nsub < 2; ++nsub) {
            int col = j0 + nsub * 16 + lr;
            float biR = bi[col], bhR = bh[col];
            float biZ = bi[128 + col], bhZ = bh[128 + col];
            float biN = bi[256 + col], bhN = bh[256 + col];
#pragma unroll
            for (int r = 0; r < 4; ++r) {
                int row = row0 + m * 16 + (l >> 4) * 4 + r;
                if (row < n) {
                    float rg = sigmoidf_(gi[0][m][nsub][r] + biR + gh[0][m][nsub][r] + bhR);
                    float zg = sigmoidf_(gi[1][m][nsub][r] + biZ + gh[1][m][nsub][r] + bhZ);
                    float ng = tanhf(gi[2][m][nsub][r] + biN + rg * (gh[2][m][nsub][r] + bhN));
                    float hv = h[(size_t)row * 128 + col];
                    out[(size_t)row * 128 + col] = (1.f - zg) * ng + zg * hv;
                }
            }
        }
    }
}

extern "C" void kernel_launch(void* const* d_in, const int* in_sizes, int n_in,
                              void* d_out, int out_size, void* d_ws, size_t ws_size,
                              hipStream_t stream)
{
    const float* h     = (const float*)d_in[0];
    const int*   srcv  = (const int*)d_in[1];
    const int*   dstv  = (const int*)d_in[2];
    const float* W     = (const float*)d_in[3];
    const float* b_W   = (const float*)d_in[4];
    const float* a_src = (const float*)d_in[5];
    const float* a_dst = (const float*)d_in[6];
    const float* a_b   = (const float*)d_in[7];
    const float* res_W = (const float*)d_in[8];
    const float* res_b = (const float*)d_in[9];
    const float* Wi    = (const float*)d_in[10];
    const float* Whg   = (const float*)d_in[11];
    const float* bi    = (const float*)d_in[12];
    const float* bh    = (const float*)d_in[13];
    float* out = (float*)d_out;
    const int n = in_sizes[0] / 128;
    const int e = in_sizes[1];
    const int nb = (n + 255) / 256;

    char* p = (char*)d_ws;
    auto carve = [&](size_t bytes) -> char* {
        char* r = p;
        p += (bytes + 255) & ~(size_t)255;
        return r;
    };
    unsigned short* h_bf   = (unsigned short*)carve((size_t)n * 128 * 2);
    unsigned short* Wh     = (unsigned short*)carve((size_t)n * 128 * 2);
    unsigned short* hres   = (unsigned short*)carve((size_t)n * 128 * 2);
    unsigned short* hp_bf  = (unsigned short*)carve((size_t)n * 128 * 2);
    float* s_s             = (float*)carve((size_t)n * 4);
    float* s_d             = (float*)carve((size_t)n * 4);
    int*   hist            = (int*)carve((size_t)n * 4);
    int*   row_start       = (int*)carve((size_t)(n + 1) * 4);
    int*   cursor          = (int*)carve((size_t)n * 4);
    int*   esrc            = (int*)carve((size_t)e * 4);
    int*   bsum            = (int*)carve((size_t)nb * 4);
    unsigned short* Wcat   = (unsigned short*)carve(32768 * 2);
    unsigned short* Wi_bf  = (unsigned short*)carve(49152 * 2);
    unsigned short* Whg_bf = (unsigned short*)carve(49152 * 2);
    float* bias_cat        = (float*)carve(256 * 4);
    float* va              = (float*)carve(256 * 4);
    float* cc              = (float*)carve(2 * 4);

    k_va<<<1, 128, 0, stream>>>(W, a_src, a_dst, b_W, va, cc);
    k_prep<<<(n * 16 + 255) / 256, 256, 0, stream>>>(h, W, res_W, b_W, res_b, Wi, Whg,
                                    va, cc, h_bf, Wcat, Wi_bf, Whg_bf, bias_cat, s_s, s_d, hist, n);
    k_hist<<<(e + 255) / 256, 256, 0, stream>>>(dstv, hist, e);
    k_bsum<<<nb, 256, 0, stream>>>(hist, bsum, n);
    k_bscan<<<1, 256, 0, stream>>>(bsum, nb);
    k_scan3<<<nb, 256, 0, stream>>>(hist, bsum, row_start, cursor, n, e);
    k_place<<<(e + 255) / 256, 256, 0, stream>>>(dstv, srcv, cursor, esrc, e);
    k_whres<<<(n + 31) / 32, 256, 0, stream>>>(h_bf, Wcat, bias_cat, Wh, hres, n);
    k_attn<<<((size_t)n * 64 + 255) / 256, 256, 0, stream>>>(row_start, esrc, s_s, s_d, a_b, Wh, hres, hp_bf, n);
    k_gru<<<(n + 31) / 32, 256, 0, stream>>>(hp_bf, h_bf, Wi_bf, Whg_bf, bi, bh, h, out, n);
}